// Round 9
// baseline (110.623 us; speedup 1.0000x reference)
//
#include <hip/hip_runtime.h>

#define B 16
#define K 256
#define Z 128
#define H 128

typedef _Float16 h2 __attribute__((ext_vector_type(2)));
typedef _Float16 half8 __attribute__((ext_vector_type(8)));
typedef float f32x4 __attribute__((ext_vector_type(4)));
union UH2 { unsigned int u; h2 h; };

// convert 8 consecutive f32 -> half8 (v_cvt_pkrtz x4)
__device__ __forceinline__ half8 cvt8(const float* __restrict__ p) {
    const float4 v0 = *(const float4*)p;
    const float4 v1 = *(const float4*)(p + 4);
    half8 t;
    t[0] = (_Float16)v0.x; t[1] = (_Float16)v0.y;
    t[2] = (_Float16)v0.z; t[3] = (_Float16)v0.w;
    t[4] = (_Float16)v1.x; t[5] = (_Float16)v1.y;
    t[6] = (_Float16)v1.z; t[7] = (_Float16)v1.w;
    return t;
}

// ---------------- K1: m1z/m2z = z@W^T + b via MFMA f16 (f16 out) ----------
// grid 256 x 16 rows; block 512 = 8 waves = (mat: W1/W2) x (n-group of 32)
__global__ __launch_bounds__(512) void k_lin(
    const float* __restrict__ z,
    const float* __restrict__ W1, const float* __restrict__ b1,
    const float* __restrict__ W2, const float* __restrict__ b2,
    _Float16* __restrict__ m1f, _Float16* __restrict__ m2f)
{
    const int row0 = blockIdx.x * 16;
    const int tid = threadIdx.x;
    const int lane = tid & 63, wave = tid >> 6;
    const int mat = wave >> 2;          // 0: W1 path, 1: W2 path
    const int ng  = wave & 3;           // n-group: 32 outputs
    const int mcol = lane & 15, quad = lane >> 4;

    const float* W  = mat ? W2 : W1;
    const float* bs = mat ? b2 : b1;
    _Float16*   dst = mat ? m2f : m1f;

    half8 a[4];
#pragma unroll
    for (int ks = 0; ks < 4; ++ks)
        a[ks] = cvt8(z + (row0 + mcol) * Z + ks * 32 + quad * 8);

    f32x4 acc[2];
#pragma unroll
    for (int nt = 0; nt < 2; ++nt) {
        const float bv = bs[ng * 32 + nt * 16 + mcol];
        acc[nt][0] = bv; acc[nt][1] = bv; acc[nt][2] = bv; acc[nt][3] = bv;
    }

#pragma unroll
    for (int ks = 0; ks < 4; ++ks) {
#pragma unroll
        for (int nt = 0; nt < 2; ++nt) {
            const int n = ng * 32 + nt * 16 + mcol;
            const half8 bb = cvt8(W + n * Z + ks * 32 + quad * 8);  // B[k][n]=W[n][k]
            acc[nt] = __builtin_amdgcn_mfma_f32_16x16x32_f16(a[ks], bb, acc[nt], 0, 0, 0);
        }
    }
#pragma unroll
    for (int nt = 0; nt < 2; ++nt) {
        const int n = ng * 32 + nt * 16 + mcol;
#pragma unroll
        for (int r = 0; r < 4; ++r)
            dst[(row0 + quad * 4 + r) * Z + n] = (_Float16)acc[nt][r];
    }
}

// ---------------- K2 (fused): tropical max + concat MFMA GEMM --------------
// grid (b:16, itile:16); block 512 = 8 waves = (row-half: 8 i) x (j-quarter: 64 j)
// masks: 1 f16 per (j,row) in LDS (8 KB); 1 ds_read_b128 per (wave, j) + v_perm dup
__global__ __launch_bounds__(512) void k_fused(
    const float* __restrict__ z, const int* __restrict__ P,
    const _Float16* __restrict__ m1f, const _Float16* __restrict__ m2f,
    const float* __restrict__ Wu, const float* __restrict__ bu,
    float* __restrict__ out)
{
    const int b = blockIdx.x, i0 = blockIdx.y * 16;
    const int tid = threadIdx.x, lane = tid & 63, wave = tid >> 6;

    __shared__ __align__(16) unsigned short smask[256][16]; // 8 KB: f16 mask per (j,row)
    __shared__ __align__(16) _Float16 xs[16][264];          // 8.25 KB concat rows (+pad)
    __shared__ unsigned int part[4][16][64];                // 16 KB partial maxima (h2 as u32)

    {   // xs z-half: 16 rows x 128 f16
        const int r = tid >> 5, c = (tid & 31) * 4;
        const float4 v = *(const float4*)&z[(b * K + i0 + r) * Z + c];
        UH2 p0, p1;
        p0.h[0] = (_Float16)v.x; p0.h[1] = (_Float16)v.y;
        p1.h[0] = (_Float16)v.z; p1.h[1] = (_Float16)v.w;
        uint2 o; o.x = p0.u; o.y = p1.u;
        *(uint2*)&xs[r][c] = o;
    }
#pragma unroll
    for (int g = 0; g < 2; ++g) {   // smask staging: 1024 (j,q) items, coalesced int4
        const int idx = g * 512 + tid;
        const int j = idx >> 2, q = idx & 3;
        const int4 pv = *(const int4*)(P + (b * K + j) * K + i0 + q * 4);
        uint2 o;
        o.x = (pv.x ? 0u : 0xFC00u) | ((pv.y ? 0u : 0xFC00u) << 16);
        o.y = (pv.z ? 0u : 0xFC00u) | ((pv.w ? 0u : 0xFC00u) << 16);
        *(uint2*)&smask[j][q * 4] = o;
    }
    __syncthreads();

    // ---- tropical: wave (rh, jq): rows rh*8..+8, j in [jq*64, +64)
    const int rh = wave & 1, jq = wave >> 1;
    const unsigned int* m2u = (const unsigned int*)m2f + (b * K + jq * 64) * 64 + lane;
    UH2 ninf; ninf.u = 0xFC00FC00u;
    h2 acc[8];
#pragma unroll
    for (int r = 0; r < 8; ++r) acc[r] = ninf.h;

#pragma unroll 4
    for (int jj = 0; jj < 64; ++jj) {
        UH2 v; v.u = m2u[jj * 64];                       // d-pair (L2-resident)
        const uint4 mw = *(const uint4*)&smask[jq * 64 + jj][rh * 8];  // 8 rows' f16 masks
        UH2 lo, hi;
        lo.u = __builtin_amdgcn_perm(mw.x, mw.x, 0x01000100u);
        hi.u = __builtin_amdgcn_perm(mw.x, mw.x, 0x03020302u);
        acc[0] = __builtin_elementwise_max(acc[0], v.h + lo.h);
        acc[1] = __builtin_elementwise_max(acc[1], v.h + hi.h);
        lo.u = __builtin_amdgcn_perm(mw.y, mw.y, 0x01000100u);
        hi.u = __builtin_amdgcn_perm(mw.y, mw.y, 0x03020302u);
        acc[2] = __builtin_elementwise_max(acc[2], v.h + lo.h);
        acc[3] = __builtin_elementwise_max(acc[3], v.h + hi.h);
        lo.u = __builtin_amdgcn_perm(mw.z, mw.z, 0x01000100u);
        hi.u = __builtin_amdgcn_perm(mw.z, mw.z, 0x03020302u);
        acc[4] = __builtin_elementwise_max(acc[4], v.h + lo.h);
        acc[5] = __builtin_elementwise_max(acc[5], v.h + hi.h);
        lo.u = __builtin_amdgcn_perm(mw.w, mw.w, 0x01000100u);
        hi.u = __builtin_amdgcn_perm(mw.w, mw.w, 0x03020302u);
        acc[6] = __builtin_elementwise_max(acc[6], v.h + lo.h);
        acc[7] = __builtin_elementwise_max(acc[7], v.h + hi.h);
    }
#pragma unroll
    for (int r = 0; r < 8; ++r) { UH2 t; t.h = acc[r]; part[jq][rh * 8 + r][lane] = t.u; }
    __syncthreads();

    {   // combine 4 j-quarters + m1z + relu -> xs m-half
        const int r = tid >> 5, c = (tid & 31) * 2;
        const uint2 q0 = *(const uint2*)&part[0][r][c];
        const uint2 q1 = *(const uint2*)&part[1][r][c];
        const uint2 q2 = *(const uint2*)&part[2][r][c];
        const uint2 q3 = *(const uint2*)&part[3][r][c];
        const uint2 m1 = *(const uint2*)((const unsigned int*)m1f + (b * K + i0 + r) * 64 + c);
        const h2 z2 = { (_Float16)0.0f, (_Float16)0.0f };
        UH2 a0, a1, a2, a3, m, t;
        uint2 o;
        a0.u = q0.x; a1.u = q1.x; a2.u = q2.x; a3.u = q3.x; m.u = m1.x;
        t.h = __builtin_elementwise_max(
            m.h + __builtin_elementwise_max(__builtin_elementwise_max(a0.h, a1.h),
                                            __builtin_elementwise_max(a2.h, a3.h)), z2);
        o.x = t.u;
        a0.u = q0.y; a1.u = q1.y; a2.u = q2.y; a3.u = q3.y; m.u = m1.y;
        t.h = __builtin_elementwise_max(
            m.h + __builtin_elementwise_max(__builtin_elementwise_max(a0.h, a1.h),
                                            __builtin_elementwise_max(a2.h, a3.h)), z2);
        o.y = t.u;
        *(uint2*)&xs[r][128 + 2 * c] = o;
    }
    __syncthreads();

    // ---- concat MFMA: out[i, n] = relu(xs[i,:] . Wu[n,:] + bu[n]); wave -> 16 n
    const int mcol = lane & 15, quad = lane >> 4;
    const int n = wave * 16 + mcol;
    half8 a[8];
#pragma unroll
    for (int ks = 0; ks < 8; ++ks)
        a[ks] = *(const half8*)&xs[mcol][ks * 32 + quad * 8];
    const float bv = bu[n];
    f32x4 c2; c2[0] = bv; c2[1] = bv; c2[2] = bv; c2[3] = bv;
#pragma unroll
    for (int ks = 0; ks < 8; ++ks) {
        const half8 bb = cvt8(Wu + n * 256 + ks * 32 + quad * 8);
        c2 = __builtin_amdgcn_mfma_f32_16x16x32_f16(a[ks], bb, c2, 0, 0, 0);
    }
#pragma unroll
    for (int r = 0; r < 4; ++r)
        out[(b * K + i0 + quad * 4 + r) * H + n] = fmaxf(c2[r], 0.0f);
}

extern "C" void kernel_launch(void* const* d_in, const int* in_sizes, int n_in,
                              void* d_out, int out_size, void* d_ws, size_t ws_size,
                              hipStream_t stream) {
    const float* z  = (const float*)d_in[0];
    const int*   P  = (const int*)d_in[1];
    const float* W1 = (const float*)d_in[2];
    const float* b1 = (const float*)d_in[3];
    const float* W2 = (const float*)d_in[4];
    const float* b2 = (const float*)d_in[5];
    const float* Wu = (const float*)d_in[6];
    const float* bu = (const float*)d_in[7];

    _Float16* m1f = (_Float16*)d_ws;               // 1 MB
    _Float16* m2f = m1f + B * K * Z;               // 1 MB

    // PROBE (this round): each kernel launched twice (idempotent).
    // t_lin + t_fused = (dur_us - 76.5)/2  — splits harness floor vs kernel time.
    k_lin<<<256, 512, 0, stream>>>(z, W1, b1, W2, b2, m1f, m2f);
    k_lin<<<256, 512, 0, stream>>>(z, W1, b1, W2, b2, m1f, m2f);
    k_fused<<<dim3(16, 16), 512, 0, stream>>>(z, P, m1f, m2f, Wu, bu, (float*)d_out);
    k_fused<<<dim3(16, 16), 512, 0, stream>>>(z, P, m1f, m2f, Wu, bu, (float*)d_out);
}

// Round 10
// 91.973 us; speedup vs baseline: 1.2028x; 1.2028x over previous
//
#include <hip/hip_runtime.h>

#define B 16
#define K 256
#define Z 128
#define H 128

typedef _Float16 h2 __attribute__((ext_vector_type(2)));
typedef _Float16 half8 __attribute__((ext_vector_type(8)));
typedef float f32x4 __attribute__((ext_vector_type(4)));
union UH2 { unsigned int u; h2 h; };

// convert 8 consecutive f32 -> half8 (v_cvt_pkrtz x4)
__device__ __forceinline__ half8 cvt8(const float* __restrict__ p) {
    const float4 v0 = *(const float4*)p;
    const float4 v1 = *(const float4*)(p + 4);
    half8 t;
    t[0] = (_Float16)v0.x; t[1] = (_Float16)v0.y;
    t[2] = (_Float16)v0.z; t[3] = (_Float16)v0.w;
    t[4] = (_Float16)v1.x; t[5] = (_Float16)v1.y;
    t[6] = (_Float16)v1.z; t[7] = (_Float16)v1.w;
    return t;
}

// ---------------- K1: m1z/m2z = z@W^T + b via MFMA f16 (f16 out) ----------
// (unchanged from R8 best) grid 256 x 16 rows; block 512 = 8 waves
__global__ __launch_bounds__(512) void k_lin(
    const float* __restrict__ z,
    const float* __restrict__ W1, const float* __restrict__ b1,
    const float* __restrict__ W2, const float* __restrict__ b2,
    _Float16* __restrict__ m1f, _Float16* __restrict__ m2f)
{
    const int row0 = blockIdx.x * 16;
    const int tid = threadIdx.x;
    const int lane = tid & 63, wave = tid >> 6;
    const int mat = wave >> 2;
    const int ng  = wave & 3;
    const int mcol = lane & 15, quad = lane >> 4;

    const float* W  = mat ? W2 : W1;
    const float* bs = mat ? b2 : b1;
    _Float16*   dst = mat ? m2f : m1f;

    half8 a[4];
#pragma unroll
    for (int ks = 0; ks < 4; ++ks)
        a[ks] = cvt8(z + (row0 + mcol) * Z + ks * 32 + quad * 8);

    f32x4 acc[2];
#pragma unroll
    for (int nt = 0; nt < 2; ++nt) {
        const float bv = bs[ng * 32 + nt * 16 + mcol];
        acc[nt][0] = bv; acc[nt][1] = bv; acc[nt][2] = bv; acc[nt][3] = bv;
    }

#pragma unroll
    for (int ks = 0; ks < 4; ++ks) {
#pragma unroll
        for (int nt = 0; nt < 2; ++nt) {
            const int n = ng * 32 + nt * 16 + mcol;
            const half8 bb = cvt8(W + n * Z + ks * 32 + quad * 8);
            acc[nt] = __builtin_amdgcn_mfma_f32_16x16x32_f16(a[ks], bb, acc[nt], 0, 0, 0);
        }
    }
#pragma unroll
    for (int nt = 0; nt < 2; ++nt) {
        const int n = ng * 32 + nt * 16 + mcol;
#pragma unroll
        for (int r = 0; r < 4; ++r)
            dst[(row0 + quad * 4 + r) * Z + n] = (_Float16)acc[nt][r];
    }
}

// ---------------- K2 (fused): tropical max + concat MFMA GEMM --------------
// grid (b:16, itile:16); block 512 = 8 waves = (row-half: 8 i) x (j-quarter: 64 j)
// Masks are wave-uniform per (i,j): packed into SGPRs via __ballot (lane = j).
// Inner iter: 1 coalesced global load + 8x{s_select + v_pk_add + v_pk_max}. No LDS.
__global__ __launch_bounds__(512) void k_fused(
    const float* __restrict__ z, const int* __restrict__ P,
    const _Float16* __restrict__ m1f, const _Float16* __restrict__ m2f,
    const float* __restrict__ Wu, const float* __restrict__ bu,
    float* __restrict__ out)
{
    const int b = blockIdx.x, i0 = blockIdx.y * 16;
    const int tid = threadIdx.x, lane = tid & 63, wave = tid >> 6;

    __shared__ unsigned char sm8[256][16];           // 4 KB: 1 byte per (j,row)
    __shared__ __align__(16) _Float16 xs[16][264];   // 8.25 KB concat rows (+pad)
    __shared__ unsigned int part[4][16][64];         // 16 KB partial maxima (h2 as u32)

    {   // xs z-half: 16 rows x 128 f16
        const int r = tid >> 5, c = (tid & 31) * 4;
        const float4 v = *(const float4*)&z[(b * K + i0 + r) * Z + c];
        UH2 p0, p1;
        p0.h[0] = (_Float16)v.x; p0.h[1] = (_Float16)v.y;
        p1.h[0] = (_Float16)v.z; p1.h[1] = (_Float16)v.w;
        uint2 o; o.x = p0.u; o.y = p1.u;
        *(uint2*)&xs[r][c] = o;
    }
#pragma unroll
    for (int g = 0; g < 2; ++g) {   // sm8 staging: coalesced int4 reads of P rows
        const int idx = g * 512 + tid;
        const int j = idx >> 2, q = idx & 3;
        const int4 pv = *(const int4*)(P + (b * K + j) * K + i0 + q * 4);
        const unsigned int byts = (pv.x ? 1u : 0u) | ((pv.y ? 1u : 0u) << 8) |
                                  ((pv.z ? 1u : 0u) << 16) | ((pv.w ? 1u : 0u) << 24);
        *(unsigned int*)&sm8[j][q * 4] = byts;
    }
    __syncthreads();

    // ---- tropical: wave (rh, jq): rows rh*8..+8, j in [jq*64, +64)
    const int rh = wave & 1, jq = wave >> 1;

    // pack this wave's masks into SGPRs: bits[r] bit l = P-active for (row, j=jq*64+l)
    unsigned long long bits[8];
#pragma unroll
    for (int r = 0; r < 8; ++r) {
        const unsigned char a = sm8[jq * 64 + lane][rh * 8 + r];
        bits[r] = __ballot(a != 0);
    }

    const unsigned int* m2u = (const unsigned int*)m2f + (b * K + jq * 64) * 64 + lane;
    UH2 ninf; ninf.u = 0xFC00FC00u;
    h2 acc[8];
#pragma unroll
    for (int r = 0; r < 8; ++r) acc[r] = ninf.h;

#pragma unroll 8
    for (int jj = 0; jj < 64; ++jj) {
        UH2 v; v.u = m2u[jj * 64];                   // d-pair, coalesced, L2-resident
#pragma unroll
        for (int r = 0; r < 8; ++r) {
            UH2 mu; mu.u = ((bits[r] >> jj) & 1ull) ? 0u : 0xFC00FC00u;  // s_cselect
            acc[r] = __builtin_elementwise_max(acc[r], v.h + mu.h);
        }
    }
#pragma unroll
    for (int r = 0; r < 8; ++r) { UH2 t; t.h = acc[r]; part[jq][rh * 8 + r][lane] = t.u; }
    __syncthreads();

    {   // combine 4 j-quarters + m1z + relu -> xs m-half
        const int r = tid >> 5, c = (tid & 31) * 2;
        const uint2 q0 = *(const uint2*)&part[0][r][c];
        const uint2 q1 = *(const uint2*)&part[1][r][c];
        const uint2 q2 = *(const uint2*)&part[2][r][c];
        const uint2 q3 = *(const uint2*)&part[3][r][c];
        const uint2 m1 = *(const uint2*)((const unsigned int*)m1f + (b * K + i0 + r) * 64 + c);
        const h2 z2 = { (_Float16)0.0f, (_Float16)0.0f };
        UH2 a0, a1, a2, a3, m, t;
        uint2 o;
        a0.u = q0.x; a1.u = q1.x; a2.u = q2.x; a3.u = q3.x; m.u = m1.x;
        t.h = __builtin_elementwise_max(
            m.h + __builtin_elementwise_max(__builtin_elementwise_max(a0.h, a1.h),
                                            __builtin_elementwise_max(a2.h, a3.h)), z2);
        o.x = t.u;
        a0.u = q0.y; a1.u = q1.y; a2.u = q2.y; a3.u = q3.y; m.u = m1.y;
        t.h = __builtin_elementwise_max(
            m.h + __builtin_elementwise_max(__builtin_elementwise_max(a0.h, a1.h),
                                            __builtin_elementwise_max(a2.h, a3.h)), z2);
        o.y = t.u;
        *(uint2*)&xs[r][128 + 2 * c] = o;
    }
    __syncthreads();

    // ---- concat MFMA: out[i, n] = relu(xs[i,:] . Wu[n,:] + bu[n]); wave -> 16 n
    const int mcol = lane & 15, quad = lane >> 4;
    const int n = wave * 16 + mcol;
    half8 a[8];
#pragma unroll
    for (int ks = 0; ks < 8; ++ks)
        a[ks] = *(const half8*)&xs[mcol][ks * 32 + quad * 8];
    const float bv = bu[n];
    f32x4 c2; c2[0] = bv; c2[1] = bv; c2[2] = bv; c2[3] = bv;
#pragma unroll
    for (int ks = 0; ks < 8; ++ks) {
        const half8 bb = cvt8(Wu + n * 256 + ks * 32 + quad * 8);
        c2 = __builtin_amdgcn_mfma_f32_16x16x32_f16(a[ks], bb, c2, 0, 0, 0);
    }
#pragma unroll
    for (int r = 0; r < 4; ++r)
        out[(b * K + i0 + quad * 4 + r) * H + n] = fmaxf(c2[r], 0.0f);
}

extern "C" void kernel_launch(void* const* d_in, const int* in_sizes, int n_in,
                              void* d_out, int out_size, void* d_ws, size_t ws_size,
                              hipStream_t stream) {
    const float* z  = (const float*)d_in[0];
    const int*   P  = (const int*)d_in[1];
    const float* W1 = (const float*)d_in[2];
    const float* b1 = (const float*)d_in[3];
    const float* W2 = (const float*)d_in[4];
    const float* b2 = (const float*)d_in[5];
    const float* Wu = (const float*)d_in[6];
    const float* bu = (const float*)d_in[7];

    _Float16* m1f = (_Float16*)d_ws;               // 1 MB
    _Float16* m2f = m1f + B * K * Z;               // 1 MB

    k_lin<<<256, 512, 0, stream>>>(z, W1, b1, W2, b2, m1f, m2f);
    k_fused<<<dim3(16, 16), 512, 0, stream>>>(z, P, m1f, m2f, Wu, bu, (float*)d_out);
}

// Round 11
// 88.508 us; speedup vs baseline: 1.2499x; 1.0391x over previous
//
#include <hip/hip_runtime.h>

#define B 16
#define K 256
#define Z 128
#define H 128

typedef _Float16 h2 __attribute__((ext_vector_type(2)));
typedef _Float16 half8 __attribute__((ext_vector_type(8)));
typedef float f32x4 __attribute__((ext_vector_type(4)));
union UH2 { unsigned int u; h2 h; };

// convert 8 consecutive f32 -> half8 (v_cvt_pkrtz x4)
__device__ __forceinline__ half8 cvt8(const float* __restrict__ p) {
    const float4 v0 = *(const float4*)p;
    const float4 v1 = *(const float4*)(p + 4);
    half8 t;
    t[0] = (_Float16)v0.x; t[1] = (_Float16)v0.y;
    t[2] = (_Float16)v0.z; t[3] = (_Float16)v0.w;
    t[4] = (_Float16)v1.x; t[5] = (_Float16)v1.y;
    t[6] = (_Float16)v1.z; t[7] = (_Float16)v1.w;
    return t;
}

// ---------------- K1: m1z/m2z = z@W^T + b via MFMA f16 (f16 out) ----------
// grid 256 x 16 rows; block 512 = 8 waves = (mat: W1/W2) x (n-group of 32)
__global__ __launch_bounds__(512) void k_lin(
    const float* __restrict__ z,
    const float* __restrict__ W1, const float* __restrict__ b1,
    const float* __restrict__ W2, const float* __restrict__ b2,
    _Float16* __restrict__ m1f, _Float16* __restrict__ m2f)
{
    const int row0 = blockIdx.x * 16;
    const int tid = threadIdx.x;
    const int lane = tid & 63, wave = tid >> 6;
    const int mat = wave >> 2;          // 0: W1 path, 1: W2 path
    const int ng  = wave & 3;           // n-group: 32 outputs
    const int mcol = lane & 15, quad = lane >> 4;

    const float* W  = mat ? W2 : W1;
    const float* bs = mat ? b2 : b1;
    _Float16*   dst = mat ? m2f : m1f;

    // A-frags: A[m=mcol][k=ks*32+quad*8+j] from f32 z
    half8 a[4];
#pragma unroll
    for (int ks = 0; ks < 4; ++ks)
        a[ks] = cvt8(z + (row0 + mcol) * Z + ks * 32 + quad * 8);

    f32x4 acc[2];
#pragma unroll
    for (int nt = 0; nt < 2; ++nt) {
        const float bv = bs[ng * 32 + nt * 16 + mcol];
        acc[nt][0] = bv; acc[nt][1] = bv; acc[nt][2] = bv; acc[nt][3] = bv;
    }

#pragma unroll
    for (int ks = 0; ks < 4; ++ks) {
#pragma unroll
        for (int nt = 0; nt < 2; ++nt) {
            const int n = ng * 32 + nt * 16 + mcol;
            const half8 bb = cvt8(W + n * Z + ks * 32 + quad * 8);  // B[k][n]=W[n][k]
            acc[nt] = __builtin_amdgcn_mfma_f32_16x16x32_f16(a[ks], bb, acc[nt], 0, 0, 0);
        }
    }
    // C/D: col = lane&15, row = quad*4 + reg
#pragma unroll
    for (int nt = 0; nt < 2; ++nt) {
        const int n = ng * 32 + nt * 16 + mcol;
#pragma unroll
        for (int r = 0; r < 4; ++r)
            dst[(row0 + quad * 4 + r) * Z + n] = (_Float16)acc[nt][r];
    }
}

// ---------------- K2 (fused): tropical max + concat MFMA GEMM --------------
// grid (b:16, itile:16); block 512 = 8 waves = (row-half: 8 i) x (j-quarter: 64 j)
// Inner iter: 1 coalesced global load + 2 broadcast ds_read_b128 (h2-duplicated
// masks for 8 rows) + 8x{v_pk_add + v_pk_max}. Measured local optimum (R8-R10).
__global__ __launch_bounds__(512) void k_fused(
    const float* __restrict__ z, const int* __restrict__ P,
    const _Float16* __restrict__ m1f, const _Float16* __restrict__ m2f,
    const float* __restrict__ Wu, const float* __restrict__ bu,
    float* __restrict__ out)
{
    const int b = blockIdx.x, i0 = blockIdx.y * 16;
    const int tid = threadIdx.x, lane = tid & 63, wave = tid >> 6;

    __shared__ unsigned int smask[256][16];          // 16 KB: h2 mask (0 / -inf,-inf) per (j,row)
    __shared__ __align__(16) _Float16 xs[16][264];   // 8.25 KB concat rows (+pad)
    __shared__ unsigned int part[4][16][64];         // 16 KB partial maxima (h2 as u32)

    {   // xs z-half: 16 rows x 128 f16; thread (r=tid>>5, c=(tid&31)*4)
        const int r = tid >> 5, c = (tid & 31) * 4;
        const float4 v = *(const float4*)&z[(b * K + i0 + r) * Z + c];
        UH2 p0, p1;
        p0.h[0] = (_Float16)v.x; p0.h[1] = (_Float16)v.y;
        p1.h[0] = (_Float16)v.z; p1.h[1] = (_Float16)v.w;
        uint2 o; o.x = p0.u; o.y = p1.u;
        *(uint2*)&xs[r][c] = o;
    }
#pragma unroll
    for (int g = 0; g < 2; ++g) {   // smask: 1024 (j,q) items over 512 threads
        const int idx = g * 512 + tid;
        const int j = idx >> 2, q = idx & 3;
        const int4 pv = *(const int4*)(P + (b * K + j) * K + i0 + q * 4);
        uint4 o;
        o.x = pv.x ? 0u : 0xFC00FC00u;
        o.y = pv.y ? 0u : 0xFC00FC00u;
        o.z = pv.z ? 0u : 0xFC00FC00u;
        o.w = pv.w ? 0u : 0xFC00FC00u;
        *(uint4*)&smask[j][q * 4] = o;
    }
    __syncthreads();

    // ---- tropical: wave (rh, jq): rows rh*8..+8, j in [jq*64, +64)
    const int rh = wave & 1, jq = wave >> 1;
    const unsigned int* m2u = (const unsigned int*)m2f + (b * K + jq * 64) * 64 + lane;
    UH2 ninf; ninf.u = 0xFC00FC00u;
    h2 acc[8];
#pragma unroll
    for (int r = 0; r < 8; ++r) acc[r] = ninf.h;

#pragma unroll 4
    for (int jj = 0; jj < 64; ++jj) {
        UH2 v; v.u = m2u[jj * 64];                       // d-pair (L2-resident)
        const uint4 ma = *(const uint4*)&smask[jq * 64 + jj][rh * 8];
        const uint4 mb = *(const uint4*)&smask[jq * 64 + jj][rh * 8 + 4];
        UH2 t;
        t.u = ma.x; acc[0] = __builtin_elementwise_max(acc[0], v.h + t.h);
        t.u = ma.y; acc[1] = __builtin_elementwise_max(acc[1], v.h + t.h);
        t.u = ma.z; acc[2] = __builtin_elementwise_max(acc[2], v.h + t.h);
        t.u = ma.w; acc[3] = __builtin_elementwise_max(acc[3], v.h + t.h);
        t.u = mb.x; acc[4] = __builtin_elementwise_max(acc[4], v.h + t.h);
        t.u = mb.y; acc[5] = __builtin_elementwise_max(acc[5], v.h + t.h);
        t.u = mb.z; acc[6] = __builtin_elementwise_max(acc[6], v.h + t.h);
        t.u = mb.w; acc[7] = __builtin_elementwise_max(acc[7], v.h + t.h);
    }
#pragma unroll
    for (int r = 0; r < 8; ++r) { UH2 t; t.h = acc[r]; part[jq][rh * 8 + r][lane] = t.u; }
    __syncthreads();

    {   // combine 4 j-quarters + m1z + relu -> xs m-half
        const int r = tid >> 5, c = (tid & 31) * 2;      // c: d-pair index (0..62)
        const uint2 q0 = *(const uint2*)&part[0][r][c];
        const uint2 q1 = *(const uint2*)&part[1][r][c];
        const uint2 q2 = *(const uint2*)&part[2][r][c];
        const uint2 q3 = *(const uint2*)&part[3][r][c];
        const uint2 m1 = *(const uint2*)((const unsigned int*)m1f + (b * K + i0 + r) * 64 + c);
        const h2 z2 = { (_Float16)0.0f, (_Float16)0.0f };
        UH2 a0, a1, a2, a3, m, t;
        uint2 o;
        a0.u = q0.x; a1.u = q1.x; a2.u = q2.x; a3.u = q3.x; m.u = m1.x;
        t.h = __builtin_elementwise_max(
            m.h + __builtin_elementwise_max(__builtin_elementwise_max(a0.h, a1.h),
                                            __builtin_elementwise_max(a2.h, a3.h)), z2);
        o.x = t.u;
        a0.u = q0.y; a1.u = q1.y; a2.u = q2.y; a3.u = q3.y; m.u = m1.y;
        t.h = __builtin_elementwise_max(
            m.h + __builtin_elementwise_max(__builtin_elementwise_max(a0.h, a1.h),
                                            __builtin_elementwise_max(a2.h, a3.h)), z2);
        o.y = t.u;
        *(uint2*)&xs[r][128 + 2 * c] = o;
    }
    __syncthreads();

    // ---- concat MFMA: out[i, n] = relu(xs[i,:] . Wu[n,:] + bu[n]); wave -> 16 n
    const int mcol = lane & 15, quad = lane >> 4;
    const int n = wave * 16 + mcol;
    half8 a[8];
#pragma unroll
    for (int ks = 0; ks < 8; ++ks)
        a[ks] = *(const half8*)&xs[mcol][ks * 32 + quad * 8];
    const float bv = bu[n];
    f32x4 c2; c2[0] = bv; c2[1] = bv; c2[2] = bv; c2[3] = bv;
#pragma unroll
    for (int ks = 0; ks < 8; ++ks) {
        const half8 bb = cvt8(Wu + n * 256 + ks * 32 + quad * 8);
        c2 = __builtin_amdgcn_mfma_f32_16x16x32_f16(a[ks], bb, c2, 0, 0, 0);
    }
#pragma unroll
    for (int r = 0; r < 4; ++r)
        out[(b * K + i0 + quad * 4 + r) * H + n] = fmaxf(c2[r], 0.0f);
}

extern "C" void kernel_launch(void* const* d_in, const int* in_sizes, int n_in,
                              void* d_out, int out_size, void* d_ws, size_t ws_size,
                              hipStream_t stream) {
    const float* z  = (const float*)d_in[0];
    const int*   P  = (const int*)d_in[1];
    const float* W1 = (const float*)d_in[2];
    const float* b1 = (const float*)d_in[3];
    const float* W2 = (const float*)d_in[4];
    const float* b2 = (const float*)d_in[5];
    const float* Wu = (const float*)d_in[6];
    const float* bu = (const float*)d_in[7];

    _Float16* m1f = (_Float16*)d_ws;               // 1 MB
    _Float16* m2f = m1f + B * K * Z;               // 1 MB

    k_lin<<<256, 512, 0, stream>>>(z, W1, b1, W2, b2, m1f, m2f);
    k_fused<<<dim3(16, 16), 512, 0, stream>>>(z, P, m1f, m2f, Wu, bu, (float*)d_out);
}